// Round 1
// 590.996 us; speedup vs baseline: 1.1476x; 1.1476x over previous
//
#include <hip/hip_runtime.h>
#include <cstdint>
#include <cstddef>

// ---------------------------------------------------------------------------
// CausalSelfAttention, B=4 T=2048 C=2048 H=16 D=128, fp32 in/out.
// cvt(fp32->bf16) -> gemm_qkv (256x256 8-phase counted-vmcnt schedule, fused
// rope epilogue; Q,K (B,H,T,D), V^T tiled (B,H,32,128,64)) -> fattn (flash,
// unchanged) -> gemm_proj (256x256 8-phase, fp32 out).
// GEMM structure = m201-style 8-phase: BK=64, 8 waves (2Mx4N), 128KiB dyn LDS
// double-buffer, per phase {ds_read subtile | 2x global_load_lds | barrier |
// lgkmcnt(0) | setprio(1) 16xMFMA setprio(0) | barrier}; vmcnt counted
// (4/2), never 0 in steady state. Stage order per tile B0..B3,A0,A2,A1,A3 so
// vmcnt(2) at tile boundary == "first 6 issues landed, A-tail in flight".
// Workspace layout (bytes):
//   0         Wq_b   (6144x2048 bf16)  25165824
//   25165824  Wp_b   (2048x2048 bf16)   8388608
//   33554432  x_b    (8192x2048 bf16)  33554432
//   67108864  Qb     (B,H,T,D bf16)    33554432
//   100663296 Kb     (B,H,T,D bf16)    33554432
//   134217728 Vt     tiled (B,H,32,128,64) bf16  33554432
//   167772160 Yb     (8192x2048 bf16)  33554432
// ---------------------------------------------------------------------------

typedef unsigned short u16;
typedef u16    u16x8 __attribute__((ext_vector_type(8)));
typedef __bf16 bf16x8 __attribute__((ext_vector_type(8)));
typedef float  f32x4 __attribute__((ext_vector_type(4)));

#define MFMA16(a, b, c) __builtin_amdgcn_mfma_f32_16x16x32_bf16( \
    __builtin_bit_cast(bf16x8, (a)), __builtin_bit_cast(bf16x8, (b)), (c), 0, 0, 0)

static __device__ __forceinline__ u16 f2b(float f) {
  unsigned u = __builtin_bit_cast(unsigned, f);
  unsigned r = (u + 0x7FFFu + ((u >> 16) & 1u)) >> 16;   // RNE
  return (u16)r;
}

// async global->LDS, 16B per lane; lds dest = (wave-uniform base) + lane*16
static __device__ __forceinline__ void gld_lds16(const void* g, void* l) {
  __builtin_amdgcn_global_load_lds(
      (__attribute__((address_space(1))) unsigned int*)(void*)(g),
      (__attribute__((address_space(3))) unsigned int*)(l),
      16, 0, 0);
}

#define BARRIER() asm volatile("s_barrier" ::: "memory")
#define LGKM0()   do { asm volatile("s_waitcnt lgkmcnt(0)" ::: "memory"); \
                       __builtin_amdgcn_sched_barrier(0); } while (0)
#define WAIT_VM(n) asm volatile("s_waitcnt vmcnt(" #n ")" ::: "memory")

// ---------------------------------------------------------------------------
// fp32 -> bf16 conversion, 8 elements/thread
// ---------------------------------------------------------------------------
__global__ __launch_bounds__(256) void cvt_bf16(const float4* __restrict__ src,
                                                u16x8* __restrict__ dst, int n8) {
  int i = blockIdx.x * 256 + threadIdx.x;
  if (i >= n8) return;
  float4 a = src[i * 2], b = src[i * 2 + 1];
  u16x8 o;
  o[0] = f2b(a.x); o[1] = f2b(a.y); o[2] = f2b(a.z); o[3] = f2b(a.w);
  o[4] = f2b(b.x); o[5] = f2b(b.y); o[6] = f2b(b.z); o[7] = f2b(b.w);
  dst[i] = o;
}

// ---------------------------------------------------------------------------
// 256x256 8-phase GEMM main loop (shared by gemm_qkv / gemm_proj).
// A: MxK row-major bf16, Bw: NxK row-major bf16 (i.e., computes A @ Bw^T).
// acc[i][j]: fragment rows wm*128+i*16, cols wn*64+j*16; C/D layout
// row=quad*4+reg, col=lane&15 within each 16x16 fragment.
// LDS per buffer: A[256][64] then B[256][64], 16B-chunk swizzle c^=(row&7).
// ---------------------------------------------------------------------------
static __device__ __forceinline__ void rdA(u16x8 (&af)[4][2], const u16* p,
                                           int cx0, int cx1) {
#pragma unroll
  for (int i = 0; i < 4; ++i) {
    af[i][0] = *(const u16x8*)(p + i * 1024 + cx0);
    af[i][1] = *(const u16x8*)(p + i * 1024 + cx1);
  }
}

static __device__ __forceinline__ void rdB(u16x8 (&bf)[2][2], const u16* p,
                                           int cx0, int cx1) {
#pragma unroll
  for (int j = 0; j < 2; ++j) {
    bf[j][0] = *(const u16x8*)(p + j * 1024 + cx0);
    bf[j][1] = *(const u16x8*)(p + j * 1024 + cx1);
  }
}

static __device__ __forceinline__ void mm16(f32x4 (&acc)[8][4], int ib, int jb,
                                            const u16x8 (&af)[4][2],
                                            const u16x8 (&bf)[2][2]) {
#pragma unroll
  for (int i = 0; i < 4; ++i)
#pragma unroll
    for (int j = 0; j < 2; ++j) {
      acc[ib + i][jb + j] = MFMA16(af[i][0], bf[j][0], acc[ib + i][jb + j]);
      acc[ib + i][jb + j] = MFMA16(af[i][1], bf[j][1], acc[ib + i][jb + j]);
    }
}

static __device__ __forceinline__ void gemm256_main(
    const u16* __restrict__ A, const u16* __restrict__ Bw, int K,
    int m0, int n0, u16* sm, f32x4 (&acc)[8][4]) {
  const int tid = threadIdx.x;
  const int lane = tid & 63, wv = tid >> 6;
  const int quad = lane >> 4, col = lane & 15;
  const int wm = wv >> 2, wn = wv & 3;

  u16* LA0 = sm;                // buf0 A  (32KB = 16384 u16)
  u16* LB0 = sm + 16384;        // buf0 B
  u16* LA1 = sm + 32768;        // buf1 A
  u16* LB1 = sm + 49152;        // buf1 B

#pragma unroll
  for (int i = 0; i < 8; ++i)
#pragma unroll
    for (int j = 0; j < 4; ++j) acc[i][j] = (f32x4){0.f, 0.f, 0.f, 0.f};

  // staging: block-wide issue u covers tile rows [u*64, u*64+64); per wave
  // 8 rows. LDS dest linear (wave-uniform base); global source pre-swizzled.
  const int r8 = lane >> 3, ch = lane & 7;
  const int sc8 = (ch ^ r8) << 3;           // row&7 == r8 for our row layout
  const u16 *aS[4], *bS[4];
  int dof[4];
#pragma unroll
  for (int u = 0; u < 4; ++u) {
    int row = u * 64 + wv * 8 + r8;
    aS[u] = A + (size_t)(m0 + row) * K + sc8;
    bS[u] = Bw + (size_t)(n0 + row) * K + sc8;
    dof[u] = (u * 64 + wv * 8) * 64;
  }

  // fragment read offsets: frag row m => m&7 == col&7 (other terms %16==0)
  const int cx0 = ((quad) ^ (col & 7)) << 3;
  const int cx1 = ((4 | quad) ^ (col & 7)) << 3;
  const int offA = (wm * 128 + col) * 64;   // + mh*4096 + i*1024
  const int offB = (wn * 64 + col) * 64;    // + jlo*1024

  // ---- prologue: stage tile0 -> buf0, order B0..B3, A0, A2, A1, A3 ----
  gld_lds16(bS[0], LB0 + dof[0]); gld_lds16(bS[1], LB0 + dof[1]);
  gld_lds16(bS[2], LB0 + dof[2]); gld_lds16(bS[3], LB0 + dof[3]);
  gld_lds16(aS[0], LA0 + dof[0]); gld_lds16(aS[2], LA0 + dof[2]);
  gld_lds16(aS[1], LA0 + dof[1]); gld_lds16(aS[3], LA0 + dof[3]);
  WAIT_VM(2);          // first 6 (B0-3, A0, A2) landed; A1,A3 in flight
  BARRIER();

  u16x8 af[4][2], bfL[2][2], bfH[2][2];
  const int nIt = K >> 7;   // K-tile pairs (even tile -> buf0, odd -> buf1)
#pragma unroll 1
  for (int it = 0; it < nIt; ++it) {
    const size_t ko = (size_t)it * 128 + 64;    // k-offset of odd tile
    const size_t kn = (size_t)it * 128 + 128;   // k-offset of next even tile
    const bool hn = (it + 1 < nIt);

    // ---------- e.q0 : acc[0..3][0..1] ----------
    rdA(af, LA0 + offA, cx0, cx1);
    rdB(bfL, LB0 + offB, cx0, cx1);
    gld_lds16(bS[0] + ko, LB1 + dof[0]); gld_lds16(bS[1] + ko, LB1 + dof[1]);
    BARRIER(); LGKM0();
    __builtin_amdgcn_s_setprio(1); mm16(acc, 0, 0, af, bfL);
    __builtin_amdgcn_s_setprio(0);
    BARRIER();
    // ---------- e.q1 : acc[0..3][2..3] ----------
    rdB(bfH, LB0 + offB + 2048, cx0, cx1);
    gld_lds16(bS[2] + ko, LB1 + dof[2]); gld_lds16(bS[3] + ko, LB1 + dof[3]);
    WAIT_VM(4);   // newest-4 = odd B0-3 -> even tile's A1,A3 landed
    BARRIER(); LGKM0();
    __builtin_amdgcn_s_setprio(1); mm16(acc, 0, 2, af, bfH);
    __builtin_amdgcn_s_setprio(0);
    BARRIER();
    // ---------- e.q2 : acc[4..7][0..1] ----------
    rdA(af, LA0 + offA + 4096, cx0, cx1);
    gld_lds16(aS[0] + ko, LA1 + dof[0]); gld_lds16(aS[2] + ko, LA1 + dof[2]);
    BARRIER(); LGKM0();
    __builtin_amdgcn_s_setprio(1); mm16(acc, 4, 0, af, bfL);
    __builtin_amdgcn_s_setprio(0);
    BARRIER();
    // ---------- e.q3 : acc[4..7][2..3] ----------
    gld_lds16(aS[1] + ko, LA1 + dof[1]); gld_lds16(aS[3] + ko, LA1 + dof[3]);
    WAIT_VM(2);   // odd tile's first 6 landed; its A1,A3 in flight
    BARRIER(); __builtin_amdgcn_sched_barrier(0);
    __builtin_amdgcn_s_setprio(1); mm16(acc, 4, 2, af, bfH);
    __builtin_amdgcn_s_setprio(0);
    BARRIER();
    // ---------- o.q0 ----------
    rdA(af, LA1 + offA, cx0, cx1);
    rdB(bfL, LB1 + offB, cx0, cx1);
    if (hn) { gld_lds16(bS[0] + kn, LB0 + dof[0]); gld_lds16(bS[1] + kn, LB0 + dof[1]); }
    BARRIER(); LGKM0();
    __builtin_amdgcn_s_setprio(1); mm16(acc, 0, 0, af, bfL);
    __builtin_amdgcn_s_setprio(0);
    BARRIER();
    // ---------- o.q1 ----------
    rdB(bfH, LB1 + offB + 2048, cx0, cx1);
    if (hn) {
      gld_lds16(bS[2] + kn, LB0 + dof[2]); gld_lds16(bS[3] + kn, LB0 + dof[3]);
      WAIT_VM(4);   // newest-4 = next-even B0-3 -> odd A1,A3 landed
    } else {
      WAIT_VM(0);   // epilogue drain: nothing newer exists
    }
    BARRIER(); LGKM0();
    __builtin_amdgcn_s_setprio(1); mm16(acc, 0, 2, af, bfH);
    __builtin_amdgcn_s_setprio(0);
    BARRIER();
    // ---------- o.q2 ----------
    rdA(af, LA1 + offA + 4096, cx0, cx1);
    if (hn) { gld_lds16(aS[0] + kn, LA0 + dof[0]); gld_lds16(aS[2] + kn, LA0 + dof[2]); }
    BARRIER(); LGKM0();
    __builtin_amdgcn_s_setprio(1); mm16(acc, 4, 0, af, bfL);
    __builtin_amdgcn_s_setprio(0);
    BARRIER();
    // ---------- o.q3 ----------
    if (hn) { gld_lds16(aS[1] + kn, LA0 + dof[1]); gld_lds16(aS[3] + kn, LA0 + dof[3]); }
    WAIT_VM(2);     // next-even first 6 landed (trivial when !hn)
    BARRIER(); __builtin_amdgcn_sched_barrier(0);
    __builtin_amdgcn_s_setprio(1); mm16(acc, 4, 2, af, bfH);
    __builtin_amdgcn_s_setprio(0);
    BARRIER();
  }
}

// ---------------------------------------------------------------------------
// GEMM1: qkv = x_b @ W_attn^T with FUSED ROPE on Q,K in the epilogue.
// 256x256 tile, 8-phase schedule. Epilogue: Q (B,H,T,D) roped, K (B,H,T,D)
// roped, V^T tiled (B,H,kt,D,64).
// ---------------------------------------------------------------------------
__global__ __launch_bounds__(512, 2) void gemm_qkv(
    const u16* __restrict__ A, const u16* __restrict__ Bw,
    const float* __restrict__ freqs, int K,
    u16* __restrict__ Qp, u16* __restrict__ Kp, u16* __restrict__ Vp) {
  extern __shared__ u16 sm[];
  const int m0 = blockIdx.y * 256, n0 = blockIdx.x * 256;
  f32x4 acc[8][4];
  gemm256_main(A, Bw, K, m0, n0, sm, acc);

  const int tid = threadIdx.x;
  const int lane = tid & 63, wv = tid >> 6;
  const int quad = lane >> 4, col = lane & 15;
  const int wm = wv >> 2, wn = wv & 3;

  const int which = n0 >> 11;          // 0=Q 1=K 2=V (256 | 2048 boundaries)
  if (which == 2) {
#pragma unroll
    for (int i = 0; i < 8; ++i) {
      int mg = m0 + wm * 128 + i * 16 + quad * 4;
#pragma unroll
      for (int j = 0; j < 4; ++j) {
        int vcol = (n0 + wn * 64 + j * 16 + col) & 2047;
        int h = vcol >> 7, d = vcol & 127;
#pragma unroll
        for (int r = 0; r < 4; ++r) {
          int m = mg + r;
          int b = m >> 11, t = m & 2047;
          // tiled V^T: [bh][t>>6][d][t&63], 16KB contiguous per kv-tile
          size_t off = ((((size_t)(b * 16 + h)) * 32 + (size_t)(t >> 6)) * 128 + (size_t)d) * 64
                       + (size_t)(t & 63);
          Vp[off] = f2b(acc[i][j][r]);
        }
      }
    }
  } else {
    u16* dst = (which == 0) ? Qp : Kp;
#pragma unroll
    for (int j = 0; j < 4; ++j) {
      int ncol = (n0 + wn * 64 + j * 16 + col) & 2047;
      int h = ncol >> 7, dd = ncol & 127;
      int jj = dd >> 1;
      bool even = (dd & 1) == 0;
      float fr = freqs[jj];
      int dout = even ? jj : jj + 64;
#pragma unroll
      for (int i = 0; i < 8; ++i) {
        int mg = m0 + wm * 128 + i * 16 + quad * 4;
#pragma unroll
        for (int r = 0; r < 4; ++r) {
          float own = acc[i][j][r];
          float par = __shfl_xor(own, 1);
          int m = mg + r;
          int b = m >> 11, t = m & 2047;
          float theta = (float)t * fr;                       // matches ref fp32 theta
          float rev = theta * 0.15915494309189535f;          // /2pi
          rev -= floorf(rev);
          float s = __builtin_amdgcn_sinf(rev);              // sin(2*pi*rev)
          float c = __builtin_amdgcn_cosf(rev);
          float outv = even ? (own * c - par * s) : (par * s + own * c);
          size_t off = ((((size_t)(b * 16 + h)) << 11 | (size_t)t) << 7) | (size_t)dout;
          dst[off] = f2b(outv);
        }
      }
    }
  }
}

// ---------------------------------------------------------------------------
// GEMM2: out = y @ W_proj^T, fp32 out. Same 256x256 8-phase structure.
// ---------------------------------------------------------------------------
__global__ __launch_bounds__(512, 2) void gemm_proj(
    const u16* __restrict__ A, const u16* __restrict__ Bw,
    int N, int K, float* __restrict__ out) {
  extern __shared__ u16 sm[];
  const int m0 = blockIdx.y * 256, n0 = blockIdx.x * 256;
  f32x4 acc[8][4];
  gemm256_main(A, Bw, K, m0, n0, sm, acc);

  const int tid = threadIdx.x;
  const int lane = tid & 63, wv = tid >> 6;
  const int quad = lane >> 4, col = lane & 15;
  const int wm = wv >> 2, wn = wv & 3;

#pragma unroll
  for (int i = 0; i < 8; ++i) {
    int mg = m0 + wm * 128 + i * 16 + quad * 4;
#pragma unroll
    for (int j = 0; j < 4; ++j) {
      int ng = n0 + wn * 64 + j * 16 + col;
#pragma unroll
      for (int r = 0; r < 4; ++r) out[(size_t)(mg + r) * N + ng] = acc[i][j][r];
    }
  }
}

// ---------------------------------------------------------------------------
// Flash attention, causal, paired q-tiles (uniform 34 kv-iters per block).
// Block (bh, p): phase0 = q-tile p (128 rows), phase1 = q-tile 15-p.
// 512 threads = 8 waves x 16 q rows. BC=64. Waves 0-3 stage K (contiguous),
// waves 4-7 stage tiled V^T (contiguous). LDS 48KB -> 2 blocks/CU, 16 waves.
// Grid (bh=64 fast, p=8): same-bh blocks land on one XCD under RR for L2 reuse.
// ---------------------------------------------------------------------------
__global__ __launch_bounds__(512, 4) void fattn(
    const u16* __restrict__ Qb, const u16* __restrict__ Kb, const u16* __restrict__ Vt,
    u16* __restrict__ Yb) {
  __shared__ alignas(16) u16 lK[64 * 128];    // [kc][d], chunk16 xor row&15
  __shared__ alignas(16) u16 lVt[128 * 64];   // [d][kc], chunk8 xor row&7
  __shared__ alignas(16) u16 lP[8][16 * 64];  // per-wave [qr][kc], chunk8 xor row&7

  const int tid = threadIdx.x;
  const int lane = tid & 63, wv = tid >> 6;    // 0..7
  const int quad = lane >> 4, col = lane & 15;
  const int bh = blockIdx.x;                   // fast dim -> XCD locality per bh
  const int p = blockIdx.y;                    // 0..7
  const int b = bh >> 4, h = bh & 15;
  const size_t base = (size_t)bh << 18;        // * 2048 * 128
  const float kcomb = 0.08838834764831845f * 1.4426950408889634f;  // 1/sqrt(D)*log2e

#pragma unroll 1
  for (int phase = 0; phase < 2; ++phase) {
    const int tq = phase ? (15 - p) : p;       // q-tile index (128 rows)
    const int qr0 = tq * 128 + wv * 16;        // wave's 16 q rows
    const int dkt = qr0 >> 6;                  // wave's diagonal kv-tile

    u16x8 qf[4];
#pragma unroll
    for (int t = 0; t < 4; ++t)
      qf[t] = *(const u16x8*)(Qb + base + (size_t)(qr0 + col) * 128 + t * 32 + quad * 8);

    f32x4 mrow = (f32x4){-1e30f, -1e30f, -1e30f, -1e30f};
    f32x4 lrow = (f32x4){0.f, 0.f, 0.f, 0.f};
    f32x4 o[8];
#pragma unroll
    for (int dt = 0; dt < 8; ++dt) o[dt] = (f32x4){0.f, 0.f, 0.f, 0.f};

    const int nkt = 2 * tq + 2;
#pragma unroll 1
    for (int kt = 0; kt < nkt; ++kt) {
      __syncthreads();
      if (wv < 4) {
        // stage K tile rows wv*16 .. +15 (contiguous 256B rows, swizzled chunks)
#pragma unroll
        for (int u = 0; u < 4; ++u) {
          int row = wv * 16 + u * 4 + (lane >> 4);
          int sc = (lane & 15) ^ (row & 15);
          gld_lds16(Kb + base + (size_t)(kt * 64 + row) * 128 + (sc << 3),
                    lK + (size_t)(wv * 16 + u * 4) * 128);
        }
      } else {
        // stage tiled V^T rows (wv-4)*32 .. +31 (contiguous 128B rows)
        int vw = wv - 4;
        const u16* vbase = Vt + ((size_t)(bh * 32 + kt) << 13);  // *128*64
#pragma unroll
        for (int u = 0; u < 4; ++u) {
          int row = vw * 32 + u * 8 + (lane >> 3);
          int sc = (lane & 7) ^ (row & 7);
          gld_lds16(vbase + (size_t)row * 64 + (sc << 3),
                    lVt + (size_t)(vw * 32 + u * 8) * 64);
        }
      }
      __syncthreads();

      if (kt <= dkt) {
        // QK^T
        f32x4 sv[4];
#pragma unroll
        for (int nt = 0; nt < 4; ++nt) {
          f32x4 s = (f32x4){0.f, 0.f, 0.f, 0.f};
#pragma unroll
          for (int t = 0; t < 4; ++t) {
            int krow = nt * 16 + col;
            u16x8 kf = *(const u16x8*)&lK[krow * 128 + ((((t << 2) | quad) ^ (krow & 15)) << 3)];
            s = MFMA16(qf[t], kf, s);
          }
          sv[nt] = s;
        }
#pragma unroll
        for (int nt = 0; nt < 4; ++nt)
#pragma unroll
          for (int r = 0; r < 4; ++r) sv[nt][r] *= kcomb;
        if (kt == dkt) {  // diagonal tile: causal mask
#pragma unroll
          for (int nt = 0; nt < 4; ++nt) {
            int cg = kt * 64 + nt * 16 + col;
#pragma unroll
            for (int r = 0; r < 4; ++r)
              if (cg > qr0 + quad * 4 + r) sv[nt][r] = -1e30f;
          }
        }
        // row max over nt and the 16 lanes holding this row
        f32x4 mx = sv[0];
#pragma unroll
        for (int nt = 1; nt < 4; ++nt)
#pragma unroll
          for (int r = 0; r < 4; ++r) mx[r] = fmaxf(mx[r], sv[nt][r]);
#pragma unroll
        for (int off = 1; off < 16; off <<= 1)
#pragma unroll
          for (int r = 0; r < 4; ++r) mx[r] = fmaxf(mx[r], __shfl_xor(mx[r], off));
        f32x4 alpha;
#pragma unroll
        for (int r = 0; r < 4; ++r) {
          float mn = fmaxf(mrow[r], mx[r]);
          alpha[r] = exp2f(mrow[r] - mn);
          mrow[r] = mn;
        }
        f32x4 ps = (f32x4){0.f, 0.f, 0.f, 0.f};
#pragma unroll
        for (int nt = 0; nt < 4; ++nt)
#pragma unroll
          for (int r = 0; r < 4; ++r) {
            float pe = exp2f(sv[nt][r] - mrow[r]);
            ps[r] += pe;
            int row = quad * 4 + r;
            int ch = ((nt << 1) | (col >> 3)) ^ (row & 7);
            lP[wv][row * 64 + (ch << 3) + (col & 7)] = f2b(pe);
          }
#pragma unroll
        for (int off = 1; off < 16; off <<= 1)
#pragma unroll
          for (int r = 0; r < 4; ++r) ps[r] += __shfl_xor(ps[r], off);
#pragma unroll
        for (int r = 0; r < 4; ++r) lrow[r] = lrow[r] * alpha[r] + ps[r];
#pragma unroll
        for (int dt = 0; dt < 8; ++dt)
#pragma unroll
          for (int r = 0; r < 4; ++r) o[dt][r] *= alpha[r];
        // PV: o += P(16x64) x V^T(64x128 as B-operand from lVt)
#pragma unroll
        for (int t = 0; t < 2; ++t) {
          u16x8 pf = *(const u16x8*)&lP[wv][col * 64 + ((((t << 2) | quad) ^ (col & 7)) << 3)];
#pragma unroll
          for (int dt = 0; dt < 8; ++dt) {
            int drow = dt * 16 + col;
            u16x8 vf = *(const u16x8*)&lVt[drow * 64 + ((((t << 2) | quad) ^ (drow & 7)) << 3)];
            o[dt] = MFMA16(pf, vf, o[dt]);
          }
        }
      }
    }  // kt

    // normalize + write Y (B*T, C) bf16
    f32x4 inv;
#pragma unroll
    for (int r = 0; r < 4; ++r) inv[r] = 1.0f / lrow[r];
#pragma unroll
    for (int dt = 0; dt < 8; ++dt)
#pragma unroll
      for (int r = 0; r < 4; ++r) {
        float y = o[dt][r] * inv[r];
        int q = qr0 + quad * 4 + r;
        Yb[((size_t)(b * 2048 + q)) * 2048 + h * 128 + dt * 16 + col] = f2b(y);
      }
  }  // phase
}

// ---------------------------------------------------------------------------
extern "C" void kernel_launch(void* const* d_in, const int* in_sizes, int n_in,
                              void* d_out, int out_size, void* d_ws, size_t ws_size,
                              hipStream_t stream) {
  (void)in_sizes; (void)n_in; (void)out_size; (void)ws_size;
  const float* x     = (const float*)d_in[0];
  const float* freqs = (const float*)d_in[1];
  const float* Wattn = (const float*)d_in[2];
  const float* Wproj = (const float*)d_in[3];
  float* out = (float*)d_out;
  char* ws = (char*)d_ws;

  u16* Wq_b = (u16*)(ws + 0);
  u16* Wp_b = (u16*)(ws + 25165824);
  u16* x_b  = (u16*)(ws + 33554432);
  u16* Qb   = (u16*)(ws + 67108864);
  u16* Kb   = (u16*)(ws + 100663296);
  u16* Vt   = (u16*)(ws + 134217728);
  u16* Yb   = (u16*)(ws + 167772160);

  static bool attr_done = false;
  if (!attr_done) {
    (void)hipFuncSetAttribute((const void*)gemm_qkv,
                              hipFuncAttributeMaxDynamicSharedMemorySize, 131072);
    (void)hipFuncSetAttribute((const void*)gemm_proj,
                              hipFuncAttributeMaxDynamicSharedMemorySize, 131072);
    attr_done = true;
  }

  cvt_bf16<<<6144, 256, 0, stream>>>((const float4*)Wattn, (u16x8*)Wq_b, 12582912 / 8);
  cvt_bf16<<<2048, 256, 0, stream>>>((const float4*)Wproj, (u16x8*)Wp_b, 4194304 / 8);
  cvt_bf16<<<8192, 256, 0, stream>>>((const float4*)x, (u16x8*)x_b, 16777216 / 8);

  gemm_qkv<<<dim3(24, 32), 512, 131072, stream>>>(x_b, Wq_b, freqs, 2048, Qb, Kb, Vt);
  fattn<<<dim3(64, 8), 512, 0, stream>>>(Qb, Kb, Vt, Yb);
  gemm_proj<<<dim3(8, 32), 512, 131072, stream>>>(Yb, Wp_b, 2048, 2048, out);
}